// Round 13
// baseline (1226.771 us; speedup 1.0000x reference)
//
#include <hip/hip_runtime.h>

#define HID 128
#define NNODES 50000
#define NEDGES 800000

typedef __attribute__((ext_vector_type(8))) short short8;
typedef __attribute__((ext_vector_type(4))) float f32x4;

union U8 { short8 v; unsigned short u[8]; };

__device__ __forceinline__ unsigned short f2b(float f) {
  unsigned int u = __float_as_uint(f);
  u += 0x7FFFu + ((u >> 16) & 1u);
  return (unsigned short)(u >> 16);
}

// packed RNE f32->bf16x2 — plain C.
// (inline-asm v_cvt_pk_bf16_f32 was proven WRONG on this target in r4 — do not reintroduce)
__device__ __forceinline__ unsigned int pk2(float a, float b) {
  unsigned int ua = __float_as_uint(a);
  ua += 0x7FFFu + ((ua >> 16) & 1u);
  unsigned int ub = __float_as_uint(b);
  ub += 0x7FFFu + ((ub >> 16) & 1u);
  return (ua >> 16) | (ub & 0xFFFF0000u);
}

// cheap round-half-up pack (tie behavior differs from RNE only)
__device__ __forceinline__ unsigned int pk2h(float a, float b) {
  unsigned int ua = __float_as_uint(a) + 0x8000u;
  unsigned int ub = __float_as_uint(b) + 0x8000u;
  return (ua >> 16) | (ub & 0xFFFF0000u);
}

// packed bf16 atomic add (gfx950 ISA; verified r3)
__device__ __forceinline__ void atomicPkAddBf16(unsigned short* addr, unsigned int packed) {
  asm volatile("global_atomic_pk_add_bf16 %0, %1, off" :: "v"(addr), "v"(packed) : "memory");
}

// stage-zone swizzle (chunks 0..15); same formula on write and read
__device__ __forceinline__ int stage_chunk(int c0, int row) {
  return ((c0 >> 3) ^ (row & 7) ^ (((row >> 2) & 3) << 1)) & 15;
}

// ---- pack weights into bf16 fragment-native layout ----
__global__ __launch_bounds__(256) void pack_kernel(
    const float* __restrict__ ew1, const float* __restrict__ ew2,
    const float* __restrict__ xw1, const float* __restrict__ nw1,
    const float* __restrict__ nw2, unsigned short* __restrict__ ws) {
  int i = blockIdx.x * 256 + threadIdx.x;
  const float* w; int base, ksrc;
  if (i < 36864)       { w = ew1; base = 0;      ksrc = 280; }
  else if (i < 53248)  { w = ew2; base = 36864;  ksrc = 128; }
  else if (i < 69632)  { w = xw1; base = 53248;  ksrc = 128; }
  else if (i < 102400) { w = nw1; base = 69632;  ksrc = 256; }
  else if (i < 118784) { w = nw2; base = 102400; ksrc = 128; }
  else return;
  int li = i - base;
  int j = li & 7, t = li >> 3;
  int col = t & 127, kg = t >> 7;
  int k = kg * 8 + j;
  float v = (k < ksrc) ? w[k * 128 + col] : 0.0f;
  ws[i] = f2b(v);
}

// ---- pre-convert h to bf16 copy hB ----
__global__ __launch_bounds__(256) void hpack_kernel(
    const float* __restrict__ h, unsigned short* __restrict__ hB) {
  int i = blockIdx.x * 256 + threadIdx.x;
  const float4* p = reinterpret_cast<const float4*>(h + (size_t)i * 8);
  float4 a = p[0], b = p[1];
  uint4 u;
  u.x = pk2(a.x, a.y); u.y = pk2(a.z, a.w);
  u.z = pk2(b.x, b.y); u.w = pk2(b.z, b.w);
  *reinterpret_cast<uint4*>(hB + (size_t)i * 8) = u;
}

// ---- counting sort by dst: hist -> scan -> scatter ----
__global__ __launch_bounds__(256) void hist_kernel(
    const int* __restrict__ dst, int* __restrict__ cnt) {
  int e = blockIdx.x * 256 + threadIdx.x;
  if (e < NEDGES) atomicAdd(&cnt[dst[e]], 1);
}

__global__ __launch_bounds__(256) void scan_kernel(int* __restrict__ cnt) {
  // single block, 256 threads, each owns 196 consecutive entries (196*256=50176>=NNODES)
  __shared__ int sums[256];
  __shared__ int offs[256];
  int t = threadIdx.x;
  int base = t * 196;
  int s = 0;
  for (int i = 0; i < 196; ++i) {
    int idx = base + i;
    if (idx < NNODES) s += cnt[idx];
  }
  sums[t] = s;
  __syncthreads();
  if (t == 0) {
    int r = 0;
    for (int i = 0; i < 256; ++i) { offs[i] = r; r += sums[i]; }
  }
  __syncthreads();
  int r = offs[t];
  for (int i = 0; i < 196; ++i) {
    int idx = base + i;
    if (idx < NNODES) { int c = cnt[idx]; cnt[idx] = r; r += c; }
  }
}

__global__ __launch_bounds__(256) void scatter_kernel(
    const int* __restrict__ dst, int* __restrict__ start, int* __restrict__ perm) {
  int e = blockIdx.x * 256 + threadIdx.x;
  if (e < NEDGES) {
    int p = atomicAdd(&start[dst[e]], 1);
    perm[p] = e;
  }
}

// ---- edge kernel: 64 edges/block, 8 waves in 2(M)x4(N) split, swapped MFMA ----
// (r11 geometry — best measured; SORTED adds perm[] indirection for dst-locality)
template<int MODE, int SORTED>
__global__ __launch_bounds__(512, 8) void edge_kernel(
    const int* __restrict__ src, const int* __restrict__ dst,
    const float* __restrict__ ef, const float* __restrict__ h,
    const float* __restrict__ x,
    const float* __restrict__ eb1, const float* __restrict__ eb2,
    const float* __restrict__ infw, const float* __restrict__ infb,
    const float* __restrict__ xb1, const float* __restrict__ xw2,
    const float* __restrict__ xb2,
    const short8* __restrict__ W1p, const short8* __restrict__ W2p,
    const short8* __restrict__ XW1p,
    const unsigned short* __restrict__ hB,
    const int* __restrict__ perm,
    float* __restrict__ miF, unsigned short* __restrict__ miB,
    float* __restrict__ dx) {
  __shared__ __align__(16) char catB[64 * 576];
  __shared__ int dL[64], sL[64];
  __shared__ float relL[64][3];
  __shared__ float ppart[8][64];   // reused as qpart
  __shared__ float eijL[64];

  const int tid = threadIdx.x;
  const int e0 = blockIdx.x * 64;
  const int lane = tid & 63, w = tid >> 6;       // w in 0..7
  const int wm = w >> 2, wn = w & 3;
  const int lr = lane & 15, lg = lane >> 4;
  const int l7 = lr & 7, l3 = lr & 3;
  const int colb = wn*32 + lr;                   // weight-frag col (j=0); j=1 adds 16
  const int c00 = wn*32 + lg*4, c01 = c00 + 16;  // lane's output cols
  const int rbase = wm*32;                       // wave's first edge row

  // phase 0 (8 threads/edge): meta + edge_feat + gaussians + pad
  {
    int row = tid >> 3, sub = tid & 7;
    int e = SORTED ? perm[e0 + row] : (e0 + row);
    int s = src[e], d = dst[e];
    if (sub == 0) { sL[row] = s; dL[row] = d; }
    float rx = x[3*d+0] - x[3*s+0];
    float ry = x[3*d+1] - x[3*s+1];
    float rz = x[3*d+2] - x[3*s+2];
    if (sub == 1) { relL[row][0] = rx; relL[row][1] = ry; relL[row][2] = rz; }
    float r = rx*rx + ry*ry + rz*rz;
    const float step = 100.0f / 19.0f;
    const float co = -0.5f / (step * step);
    if (sub < 6) {
      float v4[4];
      if (sub == 0) {
        const float4 efv = reinterpret_cast<const float4*>(ef)[e];
        v4[0]=efv.x; v4[1]=efv.y; v4[2]=efv.z; v4[3]=efv.w;
      } else {
        #pragma unroll
        for (int q = 0; q < 4; ++q) {
          float g = (float)(sub*4 - 4 + q) * step;
          float t = r - g;
          v4[q] = __expf(co * t * t);
        }
      }
      int c = sub*4;
      int chunk = (c>>3) ^ (row&7);
      uint2 pv; pv.x = pk2h(v4[0], v4[1]); pv.y = pk2h(v4[2], v4[3]);
      *reinterpret_cast<uint2*>(catB + row*576 + (chunk<<4) + ((c&7)<<1)) = pv;
    } else if (sub == 6) {
      U8 z;
      #pragma unroll
      for (int j = 0; j < 8; ++j) z.u[j] = 0;
      *reinterpret_cast<short8*>(catB + row*576 + ((32 + (3 ^ (row&3)))<<4)) = z.v;
    }
  }

  // gather h[dst] (chunks 3..18) and h[src] (chunks 19..34)
  #pragma unroll
  for (int it = 0; it < 4; ++it) {
    int i = tid + it*512;
    int row = i >> 5, c = i & 31;
    int pe = SORTED ? perm[e0 + row] : (e0 + row);
    int node = (c < 16) ? dst[pe] : src[pe];
    int chunk = 3 + c;
    int sw = (chunk < 32) ? (chunk ^ (row&7)) : (32 + ((chunk&3) ^ (row&3)));
    if (MODE == 2) {
      short8 u = *reinterpret_cast<const short8*>(hB + (size_t)node*128 + (c&15)*8);
      *reinterpret_cast<short8*>(catB + row*576 + (sw<<4)) = u;
    } else {
      const float4* hp = reinterpret_cast<const float4*>(h + (size_t)node*128 + (c&15)*8);
      float4 a = hp[0], b = hp[1];
      uint4 u;
      u.x = pk2(a.x, a.y); u.y = pk2(a.z, a.w);
      u.z = pk2(b.x, b.y); u.w = pk2(b.z, b.w);
      *reinterpret_cast<uint4*>(catB + row*576 + (sw<<4)) = u;
    }
  }

  // prefetch GEMM1 weight fragments for kt=0,1
  short8 p00 = W1p[(0*4+lg)*128 + colb], p01 = W1p[(0*4+lg)*128 + colb + 16];
  short8 p10 = W1p[(1*4+lg)*128 + colb], p11 = W1p[(1*4+lg)*128 + colb + 16];
  __syncthreads();

  // ---- GEMM1: y1 = relu(cat @ W1 + eb1), K=288 ----
  f32x4 acc[2][2];
  #pragma unroll
  for (int t = 0; t < 2; ++t) { acc[t][0] = (f32x4)0.0f; acc[t][1] = (f32x4)0.0f; }
  #pragma unroll
  for (int kt = 0; kt < 9; ++kt) {
    int ch = (kt < 8) ? ((kt*4+lg) ^ l7) : (32 + (lg ^ l3));
    short8 a0 = *reinterpret_cast<const short8*>(catB + (rbase + 0*16 + lr)*576 + (ch<<4));
    short8 a1 = *reinterpret_cast<const short8*>(catB + (rbase + 1*16 + lr)*576 + (ch<<4));
    short8 b0, b1;
    if (kt == 0)      { b0 = p00; b1 = p01; }
    else if (kt == 1) { b0 = p10; b1 = p11; }
    else              { b0 = W1p[(kt*4+lg)*128 + colb]; b1 = W1p[(kt*4+lg)*128 + colb + 16]; }
    acc[0][0] = __builtin_amdgcn_mfma_f32_16x16x32_bf16(b0, a0, acc[0][0], 0, 0, 0);
    acc[0][1] = __builtin_amdgcn_mfma_f32_16x16x32_bf16(b1, a0, acc[0][1], 0, 0, 0);
    acc[1][0] = __builtin_amdgcn_mfma_f32_16x16x32_bf16(b0, a1, acc[1][0], 0, 0, 0);
    acc[1][1] = __builtin_amdgcn_mfma_f32_16x16x32_bf16(b1, a1, acc[1][1], 0, 0, 0);
  }
  __syncthreads();  // all cat reads done before y1 overwrites zone A

  // y1 epilogue
  {
    float4 be0 = *reinterpret_cast<const float4*>(eb1 + c00);
    float4 be1 = *reinterpret_cast<const float4*>(eb1 + c01);
    #pragma unroll
    for (int t = 0; t < 2; ++t) {
      int row = rbase + t*16 + lr;
      char* rowB = catB + row*576;
      #pragma unroll
      for (int j = 0; j < 2; ++j) {
        const float4 be = j ? be1 : be0;
        int c0 = j ? c01 : c00;
        float v0 = fmaxf(acc[t][j][0] + be.x, 0.f);
        float v1 = fmaxf(acc[t][j][1] + be.y, 0.f);
        float v2 = fmaxf(acc[t][j][2] + be.z, 0.f);
        float v3 = fmaxf(acc[t][j][3] + be.w, 0.f);
        uint2 pv; pv.x = pk2h(v0, v1); pv.y = pk2h(v2, v3);
        int chunk = (c0>>3) ^ (row&7);
        *reinterpret_cast<uint2*>(rowB + (chunk<<4) + ((c0&7)<<1)) = pv;
      }
    }
  }
  __syncthreads();  // y1 visible

  // ---- GEMM2: mij = relu(y1 @ W2 + eb2), K=128 ----
  f32x4 acc2[2][2];
  #pragma unroll
  for (int t = 0; t < 2; ++t) { acc2[t][0] = (f32x4)0.0f; acc2[t][1] = (f32x4)0.0f; }
  #pragma unroll
  for (int kt = 0; kt < 4; ++kt) {
    int ch = (kt*4+lg) ^ l7;
    short8 a0 = *reinterpret_cast<const short8*>(catB + (rbase + 0*16 + lr)*576 + (ch<<4));
    short8 a1 = *reinterpret_cast<const short8*>(catB + (rbase + 1*16 + lr)*576 + (ch<<4));
    short8 b0 = W2p[(kt*4+lg)*128 + colb];
    short8 b1 = W2p[(kt*4+lg)*128 + colb + 16];
    acc2[0][0] = __builtin_amdgcn_mfma_f32_16x16x32_bf16(b0, a0, acc2[0][0], 0, 0, 0);
    acc2[0][1] = __builtin_amdgcn_mfma_f32_16x16x32_bf16(b1, a0, acc2[0][1], 0, 0, 0);
    acc2[1][0] = __builtin_amdgcn_mfma_f32_16x16x32_bf16(b0, a1, acc2[1][0], 0, 0, 0);
    acc2[1][1] = __builtin_amdgcn_mfma_f32_16x16x32_bf16(b1, a1, acc2[1][1], 0, 0, 0);
  }
  // epilogue: relu+bias kept in acc2; mij -> chunks 16..31; inf partials
  {
    float4 be0 = *reinterpret_cast<const float4*>(eb2 + c00);
    float4 be1 = *reinterpret_cast<const float4*>(eb2 + c01);
    float4 iw0 = *reinterpret_cast<const float4*>(infw + c00);
    float4 iw1 = *reinterpret_cast<const float4*>(infw + c01);
    float pl[2];
    #pragma unroll
    for (int t = 0; t < 2; ++t) {
      int row = rbase + t*16 + lr;
      char* rowB = catB + row*576;
      pl[t] = 0.f;
      #pragma unroll
      for (int j = 0; j < 2; ++j) {
        const float4 be = j ? be1 : be0;
        const float4 iw = j ? iw1 : iw0;
        int c0 = j ? c01 : c00;
        float v0 = fmaxf(acc2[t][j][0] + be.x, 0.f);
        float v1 = fmaxf(acc2[t][j][1] + be.y, 0.f);
        float v2 = fmaxf(acc2[t][j][2] + be.z, 0.f);
        float v3 = fmaxf(acc2[t][j][3] + be.w, 0.f);
        acc2[t][j][0]=v0; acc2[t][j][1]=v1; acc2[t][j][2]=v2; acc2[t][j][3]=v3;
        pl[t] += v0*iw.x + v1*iw.y + v2*iw.z + v3*iw.w;
        uint2 pv; pv.x = pk2h(v0, v1); pv.y = pk2h(v2, v3);
        int chunk = 16 + ((c0>>3) ^ (row&7));
        *reinterpret_cast<uint2*>(rowB + (chunk<<4) + ((c0&7)<<1)) = pv;
      }
    }
    #pragma unroll
    for (int t = 0; t < 2; ++t) {
      pl[t] += __shfl_xor(pl[t], 16, 64);
      pl[t] += __shfl_xor(pl[t], 32, 64);
    }
    if (lane < 16) {
      #pragma unroll
      for (int t = 0; t < 2; ++t) ppart[w][rbase + t*16 + lane] = pl[t];
    }
  }
  __syncthreads();  // sync1: mij + ppart ready

  if (tid < 64) {
    int wmr = tid >> 5;
    float s2 = infb[0] + ppart[wmr*4+0][tid] + ppart[wmr*4+1][tid]
                       + ppart[wmr*4+2][tid] + ppart[wmr*4+3][tid];
    eijL[tid] = 1.f / (1.f + __expf(-s2));
  }
  __syncthreads();  // sync2: eijL ready

  // ---- stage u = mij*eij into dead y1 zone (chunks 0..15) ----
  if (MODE >= 1) {
    #pragma unroll
    for (int t = 0; t < 2; ++t) {
      int row = rbase + t*16 + lr;
      float e = eijL[row];
      char* rowB = catB + row*576;
      #pragma unroll
      for (int j = 0; j < 2; ++j) {
        int c0 = j ? c01 : c00;
        uint2 pv;
        pv.x = pk2h(acc2[t][j][0]*e, acc2[t][j][1]*e);
        pv.y = pk2h(acc2[t][j][2]*e, acc2[t][j][3]*e);
        *reinterpret_cast<uint2*>(rowB + (stage_chunk(c0, row)<<4) + ((c0&7)<<1)) = pv;
      }
    }
  } else {
    #pragma unroll
    for (int t = 0; t < 2; ++t) {
      int row = rbase + t*16 + lr;
      int d = dL[row];
      float e = eijL[row];
      float* fp = miF + (size_t)d*128;
      #pragma unroll
      for (int j = 0; j < 2; ++j) {
        int c0 = j ? c01 : c00;
        #pragma unroll
        for (int rg = 0; rg < 4; ++rg) atomicAdd(fp + c0 + rg, acc2[t][j][rg]*e);
      }
    }
  }
  __syncthreads();  // sync2b: u staged

  // ---- coalesced scatter FIRST (GEMM3 hides atomic latency) ----
  if (MODE >= 1) {
    int col0 = wn*32 + lr*2;
    #pragma unroll
    for (int t2 = 0; t2 < 8; ++t2) {
      int row = rbase + t2*4 + lg;
      int d = dL[row];
      unsigned int val = *reinterpret_cast<const unsigned int*>(
          catB + row*576 + (stage_chunk(col0, row)<<4) + ((col0&7)<<1));
      if (val) atomicPkAddBf16(miB + (size_t)d*128 + col0, val);
    }
  }

  // ---- GEMM3: y2 = relu(mij @ XW1 + xb1); x_scale = y2 . xw2 + xb2 ----
  f32x4 acc3[2][2];
  #pragma unroll
  for (int t = 0; t < 2; ++t) { acc3[t][0] = (f32x4)0.0f; acc3[t][1] = (f32x4)0.0f; }
  #pragma unroll
  for (int kt = 0; kt < 4; ++kt) {
    int ch = 16 + ((kt*4+lg) ^ l7);
    short8 a0 = *reinterpret_cast<const short8*>(catB + (rbase + 0*16 + lr)*576 + (ch<<4));
    short8 a1 = *reinterpret_cast<const short8*>(catB + (rbase + 1*16 + lr)*576 + (ch<<4));
    short8 b0 = XW1p[(kt*4+lg)*128 + colb];
    short8 b1 = XW1p[(kt*4+lg)*128 + colb + 16];
    acc3[0][0] = __builtin_amdgcn_mfma_f32_16x16x32_bf16(b0, a0, acc3[0][0], 0, 0, 0);
    acc3[0][1] = __builtin_amdgcn_mfma_f32_16x16x32_bf16(b1, a0, acc3[0][1], 0, 0, 0);
    acc3[1][0] = __builtin_amdgcn_mfma_f32_16x16x32_bf16(b0, a1, acc3[1][0], 0, 0, 0);
    acc3[1][1] = __builtin_amdgcn_mfma_f32_16x16x32_bf16(b1, a1, acc3[1][1], 0, 0, 0);
  }
  {
    float4 bx0 = *reinterpret_cast<const float4*>(xb1 + c00);
    float4 bx1 = *reinterpret_cast<const float4*>(xb1 + c01);
    float4 xw0 = *reinterpret_cast<const float4*>(xw2 + c00);
    float4 xw1v = *reinterpret_cast<const float4*>(xw2 + c01);
    float ql[2];
    #pragma unroll
    for (int t = 0; t < 2; ++t) {
      ql[t] = 0.f;
      #pragma unroll
      for (int j = 0; j < 2; ++j) {
        const float4 bx = j ? bx1 : bx0;
        const float4 xw = j ? xw1v : xw0;
        ql[t] += fmaxf(acc3[t][j][0] + bx.x, 0.f) * xw.x
               + fmaxf(acc3[t][j][1] + bx.y, 0.f) * xw.y
               + fmaxf(acc3[t][j][2] + bx.z, 0.f) * xw.z
               + fmaxf(acc3[t][j][3] + bx.w, 0.f) * xw.w;
      }
      ql[t] += __shfl_xor(ql[t], 16, 64);
      ql[t] += __shfl_xor(ql[t], 32, 64);
    }
    if (lane < 16) {
      #pragma unroll
      for (int t = 0; t < 2; ++t) ppart[w][rbase + t*16 + lane] = ql[t];
    }
  }
  __syncthreads();  // sync3: qpart ready

  if (tid < 192) {
    int row = tid / 3, c = tid - row*3;
    int wmr = row >> 5;
    float q = xb2[0] + ppart[wmr*4+0][row] + ppart[wmr*4+1][row]
                     + ppart[wmr*4+2][row] + ppart[wmr*4+3][row];
    atomicAdd(dx + dL[row]*3 + c, relL[row][c] * q);
  }
}

// ---- node kernel: h_new = h + MLP([mi,h]); x_new = x + dx ----
template<int MODE>
__global__ __launch_bounds__(256) void node_kernel(
    const float* __restrict__ h, const float* __restrict__ x,
    const float* __restrict__ nb1, const float* __restrict__ nb2,
    const short8* __restrict__ NW1p, const short8* __restrict__ NW2p,
    const unsigned short* __restrict__ miB,
    const unsigned short* __restrict__ hB,
    float* __restrict__ out) {
  __shared__ __align__(16) char c2B[64 * 512];
  __shared__ __align__(16) char y3B[64 * 256];
  const int tid = threadIdx.x;
  const int n0 = blockIdx.x * 64;
  const float* mi = out;

  for (int i = tid; i < 64*32; i += 256) {
    int row = i >> 5, c = i & 31;
    int node = n0 + row;
    U8 u;
    if (node < NNODES) {
      if (c < 16 && MODE >= 1) {
        u.v = *reinterpret_cast<const short8*>(miB + (size_t)node*128 + c*8);
      } else if (c >= 16 && MODE == 2) {
        u.v = *reinterpret_cast<const short8*>(hB + (size_t)node*128 + (c-16)*8);
      } else {
        const float4* p = (c < 16)
          ? reinterpret_cast<const float4*>(mi + (size_t)node*128 + c*8)
          : reinterpret_cast<const float4*>(h + (size_t)node*128 + (c-16)*8);
        float4 a = p[0], b = p[1];
        uint4 uu;
        uu.x = pk2(a.x, a.y); uu.y = pk2(a.z, a.w);
        uu.z = pk2(b.x, b.y); uu.w = pk2(b.z, b.w);
        u.v = *reinterpret_cast<short8*>(&uu);
      }
    } else {
      #pragma unroll
      for (int j = 0; j < 8; ++j) u.u[j] = 0;
    }
    *reinterpret_cast<short8*>(c2B + row*512 + ((c ^ (row&7))<<4)) = u.v;
  }
  __syncthreads();

  const int lane = tid & 63, wave = tid >> 6;
  const int lr = lane & 15, lg = lane >> 4;
  const int rb = wave * 16;
  const int arow = rb + lr;

  f32x4 acc[8];
  #pragma unroll
  for (int nt = 0; nt < 8; ++nt) acc[nt] = (f32x4)0.0f;
  #pragma unroll
  for (int kt = 0; kt < 8; ++kt) {
    int chunk = kt*4 + lg;
    short8 a = *reinterpret_cast<const short8*>(c2B + arow*512 + ((chunk ^ (arow&7))<<4));
    const short8* bp = NW1p + chunk*128 + lr;
    #pragma unroll
    for (int nt = 0; nt < 8; ++nt)
      acc[nt] = __builtin_amdgcn_mfma_f32_16x16x32_bf16(a, bp[nt*16], acc[nt], 0, 0, 0);
  }
  #pragma unroll
  for (int nt = 0; nt < 8; ++nt) {
    int col = nt*16 + lr;
    float bias = nb1[col];
    #pragma unroll
    for (int r = 0; r < 4; ++r) {
      int row = rb + lg*4 + r;
      float v = fmaxf(acc[nt][r] + bias, 0.f);
      *reinterpret_cast<unsigned short*>(y3B + row*256 + (((col>>3) ^ (row&7))<<4) + ((col&7)<<1)) = f2b(v);
    }
  }

  f32x4 acc2[8];
  #pragma unroll
  for (int nt = 0; nt < 8; ++nt) acc2[nt] = (f32x4)0.0f;
  #pragma unroll
  for (int kt = 0; kt < 4; ++kt) {
    int chunk = kt*4 + lg;
    short8 a = *reinterpret_cast<const short8*>(y3B + arow*256 + ((chunk ^ (arow&7))<<4));
    const short8* bp = NW2p + chunk*128 + lr;
    #pragma unroll
    for (int nt = 0; nt < 8; ++nt)
      acc2[nt] = __builtin_amdgcn_mfma_f32_16x16x32_bf16(a, bp[nt*16], acc2[nt], 0, 0, 0);
  }
  __syncthreads();
  #pragma unroll
  for (int nt = 0; nt < 8; ++nt) {
    int col = nt*16 + lr;
    float b2 = nb2[col];
    #pragma unroll
    for (int r = 0; r < 4; ++r) {
      int row = rb + lg*4 + r;
      int node = n0 + row;
      if (node < NNODES) {
        int idx = node*128 + col;
        out[idx] = acc2[nt][r] + b2 + h[idx];
      }
    }
  }

  if (tid < 192) {
    int node = n0 + tid/3;
    if (node < NNODES) {
      int idx = node*3 + (tid%3);
      float* xo = out + NNODES*HID;
      xo[idx] = x[idx] + xo[idx];
    }
  }
}

extern "C" void kernel_launch(void* const* d_in, const int* in_sizes, int n_in,
                              void* d_out, int out_size, void* d_ws, size_t ws_size,
                              hipStream_t stream) {
  const int*   src  = (const int*)  d_in[0];
  const int*   dst  = (const int*)  d_in[1];
  const float* ef   = (const float*)d_in[2];
  const float* h    = (const float*)d_in[3];
  const float* x    = (const float*)d_in[4];
  const float* ew1  = (const float*)d_in[5];
  const float* eb1  = (const float*)d_in[6];
  const float* ew2  = (const float*)d_in[7];
  const float* eb2  = (const float*)d_in[8];
  const float* infw = (const float*)d_in[9];
  const float* infb = (const float*)d_in[10];
  const float* xw1  = (const float*)d_in[11];
  const float* xb1  = (const float*)d_in[12];
  const float* xw2  = (const float*)d_in[13];
  const float* xb2  = (const float*)d_in[14];
  const float* nw1  = (const float*)d_in[15];
  const float* nb1  = (const float*)d_in[16];
  const float* nw2  = (const float*)d_in[17];
  const float* nb2  = (const float*)d_in[18];

  float* out = (float*)d_out;
  float* miF = out;
  float* dxp = out + NNODES*HID;
  unsigned short* wsp = (unsigned short*)d_ws;
  unsigned short* miB = wsp + 118784;
  unsigned short* hBp = miB + (size_t)NNODES*HID;
  int* cntp  = (int*)(wsp + 118784 + 2*(size_t)NNODES*HID);
  int* permp = cntp + 50176;

  const size_t MIN = (size_t)NNODES*HID;
  size_t need1 = (118784u + MIN) * 2u;                               // 13.04 MB
  size_t need2 = (118784u + 2u*MIN) * 2u;                            // 25.84 MB
  size_t need3 = need2 + (50176u + (size_t)NEDGES) * 4u;             // 29.24 MB
  int mode = (ws_size >= need2) ? 2 : (ws_size >= need1 ? 1 : 0);
  int sorted = (mode == 2 && ws_size >= need3) ? 1 : 0;

  if (mode >= 1) {
    hipMemsetAsync(miB, 0, MIN*2, stream);
    hipMemsetAsync(dxp, 0, (size_t)NNODES*3*4, stream);
  } else {
    hipMemsetAsync(d_out, 0, (size_t)out_size * sizeof(float), stream);
  }

  pack_kernel<<<464, 256, 0, stream>>>(ew1, ew2, xw1, nw1, nw2, wsp);
  if (mode == 2) hpack_kernel<<<(NNODES*HID)/(256*8), 256, 0, stream>>>(h, hBp);

  if (sorted) {
    hipMemsetAsync(cntp, 0, 50176*4, stream);
    hist_kernel<<<(NEDGES+255)/256, 256, 0, stream>>>(dst, cntp);
    scan_kernel<<<1, 256, 0, stream>>>(cntp);
    scatter_kernel<<<(NEDGES+255)/256, 256, 0, stream>>>(dst, cntp, permp);
    edge_kernel<2,1><<<NEDGES/64, 512, 0, stream>>>(
        src, dst, ef, h, x, eb1, eb2, infw, infb, xb1, xw2, xb2,
        (const short8*)wsp, (const short8*)(wsp + 36864), (const short8*)(wsp + 53248),
        hBp, permp, miF, miB, dxp);
    node_kernel<2><<<(NNODES + 63)/64, 256, 0, stream>>>(
        h, x, nb1, nb2,
        (const short8*)(wsp + 69632), (const short8*)(wsp + 102400), miB, hBp, out);
  } else if (mode == 2) {
    edge_kernel<2,0><<<NEDGES/64, 512, 0, stream>>>(
        src, dst, ef, h, x, eb1, eb2, infw, infb, xb1, xw2, xb2,
        (const short8*)wsp, (const short8*)(wsp + 36864), (const short8*)(wsp + 53248),
        hBp, permp, miF, miB, dxp);
    node_kernel<2><<<(NNODES + 63)/64, 256, 0, stream>>>(
        h, x, nb1, nb2,
        (const short8*)(wsp + 69632), (const short8*)(wsp + 102400), miB, hBp, out);
  } else if (mode == 1) {
    edge_kernel<1,0><<<NEDGES/64, 512, 0, stream>>>(
        src, dst, ef, h, x, eb1, eb2, infw, infb, xb1, xw2, xb2,
        (const short8*)wsp, (const short8*)(wsp + 36864), (const short8*)(wsp + 53248),
        hBp, permp, miF, miB, dxp);
    node_kernel<1><<<(NNODES + 63)/64, 256, 0, stream>>>(
        h, x, nb1, nb2,
        (const short8*)(wsp + 69632), (const short8*)(wsp + 102400), miB, hBp, out);
  } else {
    edge_kernel<0,0><<<NEDGES/64, 512, 0, stream>>>(
        src, dst, ef, h, x, eb1, eb2, infw, infb, xb1, xw2, xb2,
        (const short8*)wsp, (const short8*)(wsp + 36864), (const short8*)(wsp + 53248),
        hBp, permp, miF, miB, dxp);
    node_kernel<0><<<(NNODES + 63)/64, 256, 0, stream>>>(
        h, x, nb1, nb2,
        (const short8*)(wsp + 69632), (const short8*)(wsp + 102400), miB, hBp, out);
  }
}

// Round 14
// 481.150 us; speedup vs baseline: 2.5497x; 2.5497x over previous
//
#include <hip/hip_runtime.h>

#define HID 128
#define NNODES 50000
#define NEDGES 800000

typedef __attribute__((ext_vector_type(8))) short short8;
typedef __attribute__((ext_vector_type(4))) float f32x4;

union U8 { short8 v; unsigned short u[8]; };

__device__ __forceinline__ unsigned short f2b(float f) {
  unsigned int u = __float_as_uint(f);
  u += 0x7FFFu + ((u >> 16) & 1u);
  return (unsigned short)(u >> 16);
}

// packed RNE f32->bf16x2 — plain C.
// (inline-asm v_cvt_pk_bf16_f32 was proven WRONG on this target in r4 — do not reintroduce)
__device__ __forceinline__ unsigned int pk2(float a, float b) {
  unsigned int ua = __float_as_uint(a);
  ua += 0x7FFFu + ((ua >> 16) & 1u);
  unsigned int ub = __float_as_uint(b);
  ub += 0x7FFFu + ((ub >> 16) & 1u);
  return (ua >> 16) | (ub & 0xFFFF0000u);
}

// cheap round-half-up pack (tie behavior differs from RNE only)
__device__ __forceinline__ unsigned int pk2h(float a, float b) {
  unsigned int ua = __float_as_uint(a) + 0x8000u;
  unsigned int ub = __float_as_uint(b) + 0x8000u;
  return (ua >> 16) | (ub & 0xFFFF0000u);
}

// packed bf16 atomic add (gfx950 ISA; verified r3)
__device__ __forceinline__ void atomicPkAddBf16(unsigned short* addr, unsigned int packed) {
  asm volatile("global_atomic_pk_add_bf16 %0, %1, off" :: "v"(addr), "v"(packed) : "memory");
}

// stage-zone swizzle (chunks 0..15); same formula on write and read.
// ((row>>3)&3) term spreads the merge-walk's rows-differing-by-8.
__device__ __forceinline__ int stage_chunk(int c0, int row) {
  return ((c0 >> 3) ^ (row & 7) ^ (((row >> 3) & 3) << 1)) & 15;
}

// ---- pack weights into bf16 fragment-native layout ----
__global__ __launch_bounds__(256) void pack_kernel(
    const float* __restrict__ ew1, const float* __restrict__ ew2,
    const float* __restrict__ xw1, const float* __restrict__ nw1,
    const float* __restrict__ nw2, unsigned short* __restrict__ ws) {
  int i = blockIdx.x * 256 + threadIdx.x;
  const float* w; int base, ksrc;
  if (i < 36864)       { w = ew1; base = 0;      ksrc = 280; }
  else if (i < 53248)  { w = ew2; base = 36864;  ksrc = 128; }
  else if (i < 69632)  { w = xw1; base = 53248;  ksrc = 128; }
  else if (i < 102400) { w = nw1; base = 69632;  ksrc = 256; }
  else if (i < 118784) { w = nw2; base = 102400; ksrc = 128; }
  else return;
  int li = i - base;
  int j = li & 7, t = li >> 3;
  int col = t & 127, kg = t >> 7;
  int k = kg * 8 + j;
  float v = (k < ksrc) ? w[k * 128 + col] : 0.0f;
  ws[i] = f2b(v);
}

// ---- pre-convert h to bf16 copy hB ----
__global__ __launch_bounds__(256) void hpack_kernel(
    const float* __restrict__ h, unsigned short* __restrict__ hB) {
  int i = blockIdx.x * 256 + threadIdx.x;
  const float4* p = reinterpret_cast<const float4*>(h + (size_t)i * 8);
  float4 a = p[0], b = p[1];
  uint4 u;
  u.x = pk2(a.x, a.y); u.y = pk2(a.z, a.w);
  u.z = pk2(b.x, b.y); u.w = pk2(b.z, b.w);
  *reinterpret_cast<uint4*>(hB + (size_t)i * 8) = u;
}

// ---- counting sort by dst: hist -> scan -> scatter ----
__global__ __launch_bounds__(256) void hist_kernel(
    const int* __restrict__ dst, int* __restrict__ cnt) {
  int e = blockIdx.x * 256 + threadIdx.x;
  if (e < NEDGES) atomicAdd(&cnt[dst[e]], 1);
}

__global__ __launch_bounds__(256) void scan_kernel(int* __restrict__ cnt) {
  __shared__ int sums[256];
  __shared__ int offs[256];
  int t = threadIdx.x;
  int base = t * 196;
  int s = 0;
  for (int i = 0; i < 196; ++i) {
    int idx = base + i;
    if (idx < NNODES) s += cnt[idx];
  }
  sums[t] = s;
  __syncthreads();
  if (t == 0) {
    int r = 0;
    for (int i = 0; i < 256; ++i) { offs[i] = r; r += sums[i]; }
  }
  __syncthreads();
  int r = offs[t];
  for (int i = 0; i < 196; ++i) {
    int idx = base + i;
    if (idx < NNODES) { int c = cnt[idx]; cnt[idx] = r; r += c; }
  }
}

__global__ __launch_bounds__(256) void scatter_kernel(
    const int* __restrict__ dst, int* __restrict__ start, int* __restrict__ perm) {
  int e = blockIdx.x * 256 + threadIdx.x;
  if (e < NEDGES) {
    int p = atomicAdd(&start[dst[e]], 1);
    perm[p] = e;
  }
}

// ---- edge kernel: 64 edges/block, 8 waves 2(M)x4(N), swapped MFMA (r11 geometry) ----
// SORTED=1: edges sorted by dst; mi scatter is segment-MERGED in LDS (one pk-atomic
// per distinct dst per col-pair, no same-address wave conflicts); dx likewise.
template<int MODE, int SORTED>
__global__ __launch_bounds__(512, 8) void edge_kernel(
    const int* __restrict__ src, const int* __restrict__ dst,
    const float* __restrict__ ef, const float* __restrict__ h,
    const float* __restrict__ x,
    const float* __restrict__ eb1, const float* __restrict__ eb2,
    const float* __restrict__ infw, const float* __restrict__ infb,
    const float* __restrict__ xb1, const float* __restrict__ xw2,
    const float* __restrict__ xb2,
    const short8* __restrict__ W1p, const short8* __restrict__ W2p,
    const short8* __restrict__ XW1p,
    const unsigned short* __restrict__ hB,
    const int* __restrict__ perm,
    float* __restrict__ miF, unsigned short* __restrict__ miB,
    float* __restrict__ dx) {
  __shared__ __align__(16) char catB[64 * 576];
  __shared__ int dL[64], sL[64];
  __shared__ float relL[64][3];
  __shared__ float ppart[8][64];   // reused as qpart
  __shared__ float eijL[64];       // reused as qL for SORTED dx merge

  const int tid = threadIdx.x;
  const int e0 = blockIdx.x * 64;
  const int lane = tid & 63, w = tid >> 6;       // w in 0..7
  const int wm = w >> 2, wn = w & 3;
  const int lr = lane & 15, lg = lane >> 4;
  const int l7 = lr & 7, l3 = lr & 3;
  const int colb = wn*32 + lr;                   // weight-frag col (j=0); j=1 adds 16
  const int c00 = wn*32 + lg*4, c01 = c00 + 16;  // lane's output cols
  const int rbase = wm*32;                       // wave's first edge row

  // phase 0 (8 threads/edge): meta + edge_feat + gaussians + pad
  {
    int row = tid >> 3, sub = tid & 7;
    int e = SORTED ? perm[e0 + row] : (e0 + row);
    int s = src[e], d = dst[e];
    if (sub == 0) { sL[row] = s; dL[row] = d; }
    float rx = x[3*d+0] - x[3*s+0];
    float ry = x[3*d+1] - x[3*s+1];
    float rz = x[3*d+2] - x[3*s+2];
    if (sub == 1) { relL[row][0] = rx; relL[row][1] = ry; relL[row][2] = rz; }
    float r = rx*rx + ry*ry + rz*rz;
    const float step = 100.0f / 19.0f;
    const float co = -0.5f / (step * step);
    if (sub < 6) {
      float v4[4];
      if (sub == 0) {
        const float4 efv = reinterpret_cast<const float4*>(ef)[e];
        v4[0]=efv.x; v4[1]=efv.y; v4[2]=efv.z; v4[3]=efv.w;
      } else {
        #pragma unroll
        for (int q = 0; q < 4; ++q) {
          float g = (float)(sub*4 - 4 + q) * step;
          float t = r - g;
          v4[q] = __expf(co * t * t);
        }
      }
      int c = sub*4;
      int chunk = (c>>3) ^ (row&7);
      uint2 pv; pv.x = pk2h(v4[0], v4[1]); pv.y = pk2h(v4[2], v4[3]);
      *reinterpret_cast<uint2*>(catB + row*576 + (chunk<<4) + ((c&7)<<1)) = pv;
    } else if (sub == 6) {
      U8 z;
      #pragma unroll
      for (int j = 0; j < 8; ++j) z.u[j] = 0;
      *reinterpret_cast<short8*>(catB + row*576 + ((32 + (3 ^ (row&3)))<<4)) = z.v;
    }
  }

  // gather h[dst] (chunks 3..18) and h[src] (chunks 19..34)
  #pragma unroll
  for (int it = 0; it < 4; ++it) {
    int i = tid + it*512;
    int row = i >> 5, c = i & 31;
    int pe = SORTED ? perm[e0 + row] : (e0 + row);
    int node = (c < 16) ? dst[pe] : src[pe];
    int chunk = 3 + c;
    int sw = (chunk < 32) ? (chunk ^ (row&7)) : (32 + ((chunk&3) ^ (row&3)));
    if (MODE == 2) {
      short8 u = *reinterpret_cast<const short8*>(hB + (size_t)node*128 + (c&15)*8);
      *reinterpret_cast<short8*>(catB + row*576 + (sw<<4)) = u;
    } else {
      const float4* hp = reinterpret_cast<const float4*>(h + (size_t)node*128 + (c&15)*8);
      float4 a = hp[0], b = hp[1];
      uint4 u;
      u.x = pk2(a.x, a.y); u.y = pk2(a.z, a.w);
      u.z = pk2(b.x, b.y); u.w = pk2(b.z, b.w);
      *reinterpret_cast<uint4*>(catB + row*576 + (sw<<4)) = u;
    }
  }

  // prefetch GEMM1 weight fragments for kt=0,1
  short8 p00 = W1p[(0*4+lg)*128 + colb], p01 = W1p[(0*4+lg)*128 + colb + 16];
  short8 p10 = W1p[(1*4+lg)*128 + colb], p11 = W1p[(1*4+lg)*128 + colb + 16];
  __syncthreads();

  // ---- GEMM1: y1 = relu(cat @ W1 + eb1), K=288 ----
  f32x4 acc[2][2];
  #pragma unroll
  for (int t = 0; t < 2; ++t) { acc[t][0] = (f32x4)0.0f; acc[t][1] = (f32x4)0.0f; }
  #pragma unroll
  for (int kt = 0; kt < 9; ++kt) {
    int ch = (kt < 8) ? ((kt*4+lg) ^ l7) : (32 + (lg ^ l3));
    short8 a0 = *reinterpret_cast<const short8*>(catB + (rbase + 0*16 + lr)*576 + (ch<<4));
    short8 a1 = *reinterpret_cast<const short8*>(catB + (rbase + 1*16 + lr)*576 + (ch<<4));
    short8 b0, b1;
    if (kt == 0)      { b0 = p00; b1 = p01; }
    else if (kt == 1) { b0 = p10; b1 = p11; }
    else              { b0 = W1p[(kt*4+lg)*128 + colb]; b1 = W1p[(kt*4+lg)*128 + colb + 16]; }
    acc[0][0] = __builtin_amdgcn_mfma_f32_16x16x32_bf16(b0, a0, acc[0][0], 0, 0, 0);
    acc[0][1] = __builtin_amdgcn_mfma_f32_16x16x32_bf16(b1, a0, acc[0][1], 0, 0, 0);
    acc[1][0] = __builtin_amdgcn_mfma_f32_16x16x32_bf16(b0, a1, acc[1][0], 0, 0, 0);
    acc[1][1] = __builtin_amdgcn_mfma_f32_16x16x32_bf16(b1, a1, acc[1][1], 0, 0, 0);
  }
  __syncthreads();  // all cat reads done before y1 overwrites zone A

  // y1 epilogue
  {
    float4 be0 = *reinterpret_cast<const float4*>(eb1 + c00);
    float4 be1 = *reinterpret_cast<const float4*>(eb1 + c01);
    #pragma unroll
    for (int t = 0; t < 2; ++t) {
      int row = rbase + t*16 + lr;
      char* rowB = catB + row*576;
      #pragma unroll
      for (int j = 0; j < 2; ++j) {
        const float4 be = j ? be1 : be0;
        int c0 = j ? c01 : c00;
        float v0 = fmaxf(acc[t][j][0] + be.x, 0.f);
        float v1 = fmaxf(acc[t][j][1] + be.y, 0.f);
        float v2 = fmaxf(acc[t][j][2] + be.z, 0.f);
        float v3 = fmaxf(acc[t][j][3] + be.w, 0.f);
        uint2 pv; pv.x = pk2h(v0, v1); pv.y = pk2h(v2, v3);
        int chunk = (c0>>3) ^ (row&7);
        *reinterpret_cast<uint2*>(rowB + (chunk<<4) + ((c0&7)<<1)) = pv;
      }
    }
  }
  __syncthreads();  // y1 visible

  // ---- GEMM2: mij = relu(y1 @ W2 + eb2), K=128 ----
  f32x4 acc2[2][2];
  #pragma unroll
  for (int t = 0; t < 2; ++t) { acc2[t][0] = (f32x4)0.0f; acc2[t][1] = (f32x4)0.0f; }
  #pragma unroll
  for (int kt = 0; kt < 4; ++kt) {
    int ch = (kt*4+lg) ^ l7;
    short8 a0 = *reinterpret_cast<const short8*>(catB + (rbase + 0*16 + lr)*576 + (ch<<4));
    short8 a1 = *reinterpret_cast<const short8*>(catB + (rbase + 1*16 + lr)*576 + (ch<<4));
    short8 b0 = W2p[(kt*4+lg)*128 + colb];
    short8 b1 = W2p[(kt*4+lg)*128 + colb + 16];
    acc2[0][0] = __builtin_amdgcn_mfma_f32_16x16x32_bf16(b0, a0, acc2[0][0], 0, 0, 0);
    acc2[0][1] = __builtin_amdgcn_mfma_f32_16x16x32_bf16(b1, a0, acc2[0][1], 0, 0, 0);
    acc2[1][0] = __builtin_amdgcn_mfma_f32_16x16x32_bf16(b0, a1, acc2[1][0], 0, 0, 0);
    acc2[1][1] = __builtin_amdgcn_mfma_f32_16x16x32_bf16(b1, a1, acc2[1][1], 0, 0, 0);
  }
  // epilogue: relu+bias kept in acc2; mij -> chunks 16..31; inf partials
  {
    float4 be0 = *reinterpret_cast<const float4*>(eb2 + c00);
    float4 be1 = *reinterpret_cast<const float4*>(eb2 + c01);
    float4 iw0 = *reinterpret_cast<const float4*>(infw + c00);
    float4 iw1 = *reinterpret_cast<const float4*>(infw + c01);
    float pl[2];
    #pragma unroll
    for (int t = 0; t < 2; ++t) {
      int row = rbase + t*16 + lr;
      char* rowB = catB + row*576;
      pl[t] = 0.f;
      #pragma unroll
      for (int j = 0; j < 2; ++j) {
        const float4 be = j ? be1 : be0;
        const float4 iw = j ? iw1 : iw0;
        int c0 = j ? c01 : c00;
        float v0 = fmaxf(acc2[t][j][0] + be.x, 0.f);
        float v1 = fmaxf(acc2[t][j][1] + be.y, 0.f);
        float v2 = fmaxf(acc2[t][j][2] + be.z, 0.f);
        float v3 = fmaxf(acc2[t][j][3] + be.w, 0.f);
        acc2[t][j][0]=v0; acc2[t][j][1]=v1; acc2[t][j][2]=v2; acc2[t][j][3]=v3;
        pl[t] += v0*iw.x + v1*iw.y + v2*iw.z + v3*iw.w;
        uint2 pv; pv.x = pk2h(v0, v1); pv.y = pk2h(v2, v3);
        int chunk = 16 + ((c0>>3) ^ (row&7));
        *reinterpret_cast<uint2*>(rowB + (chunk<<4) + ((c0&7)<<1)) = pv;
      }
    }
    #pragma unroll
    for (int t = 0; t < 2; ++t) {
      pl[t] += __shfl_xor(pl[t], 16, 64);
      pl[t] += __shfl_xor(pl[t], 32, 64);
    }
    if (lane < 16) {
      #pragma unroll
      for (int t = 0; t < 2; ++t) ppart[w][rbase + t*16 + lane] = pl[t];
    }
  }
  __syncthreads();  // sync1: mij + ppart ready

  if (tid < 64) {
    int wmr = tid >> 5;
    float s2 = infb[0] + ppart[wmr*4+0][tid] + ppart[wmr*4+1][tid]
                       + ppart[wmr*4+2][tid] + ppart[wmr*4+3][tid];
    eijL[tid] = 1.f / (1.f + __expf(-s2));
  }
  __syncthreads();  // sync2: eijL ready

  // ---- stage u = mij*eij into dead y1 zone (chunks 0..15) ----
  if (MODE >= 1) {
    #pragma unroll
    for (int t = 0; t < 2; ++t) {
      int row = rbase + t*16 + lr;
      float e = eijL[row];
      char* rowB = catB + row*576;
      #pragma unroll
      for (int j = 0; j < 2; ++j) {
        int c0 = j ? c01 : c00;
        uint2 pv;
        pv.x = pk2h(acc2[t][j][0]*e, acc2[t][j][1]*e);
        pv.y = pk2h(acc2[t][j][2]*e, acc2[t][j][3]*e);
        *reinterpret_cast<uint2*>(rowB + (stage_chunk(c0, row)<<4) + ((c0&7)<<1)) = pv;
      }
    }
  } else {
    #pragma unroll
    for (int t = 0; t < 2; ++t) {
      int row = rbase + t*16 + lr;
      int d = dL[row];
      float e = eijL[row];
      float* fp = miF + (size_t)d*128;
      #pragma unroll
      for (int j = 0; j < 2; ++j) {
        int c0 = j ? c01 : c00;
        #pragma unroll
        for (int rg = 0; rg < 4; ++rg) atomicAdd(fp + c0 + rg, acc2[t][j][rg]*e);
      }
    }
  }
  __syncthreads();  // sync2b: u staged

  // ---- mi scatter (before GEMM3 so MFMA hides atomic latency) ----
  if (MODE >= 1) {
    if (SORTED) {
      // segment-merged: lane walks 8 rows (lg quarter of the wave's 32-row half)
      // for its col-pair; one pk-atomic per dst run.
      int col0 = wn*32 + lr*2;
      int rowstart = rbase + lg*8;
      float s0 = 0.f, s1 = 0.f;
      #pragma unroll
      for (int i = 0; i < 8; ++i) {
        int row = rowstart + i;
        unsigned int val = *reinterpret_cast<const unsigned int*>(
            catB + row*576 + (stage_chunk(col0, row)<<4) + ((col0&7)<<1));
        s0 += __uint_as_float(val << 16);
        s1 += __uint_as_float(val & 0xFFFF0000u);
        bool bnd = (i == 7) || (dL[row] != dL[row+1]);
        if (bnd) {
          unsigned int packed = pk2h(s0, s1);
          if (packed) atomicPkAddBf16(miB + (size_t)dL[row]*128 + col0, packed);
          s0 = 0.f; s1 = 0.f;
        }
      }
    } else {
      int col0 = wn*32 + lr*2;
      #pragma unroll
      for (int t2 = 0; t2 < 8; ++t2) {
        int row = rbase + t2*4 + lg;
        int d = dL[row];
        unsigned int val = *reinterpret_cast<const unsigned int*>(
            catB + row*576 + (stage_chunk(col0, row)<<4) + ((col0&7)<<1));
        if (val) atomicPkAddBf16(miB + (size_t)d*128 + col0, val);
      }
    }
  }

  // ---- GEMM3: y2 = relu(mij @ XW1 + xb1); x_scale = y2 . xw2 + xb2 ----
  f32x4 acc3[2][2];
  #pragma unroll
  for (int t = 0; t < 2; ++t) { acc3[t][0] = (f32x4)0.0f; acc3[t][1] = (f32x4)0.0f; }
  #pragma unroll
  for (int kt = 0; kt < 4; ++kt) {
    int ch = 16 + ((kt*4+lg) ^ l7);
    short8 a0 = *reinterpret_cast<const short8*>(catB + (rbase + 0*16 + lr)*576 + (ch<<4));
    short8 a1 = *reinterpret_cast<const short8*>(catB + (rbase + 1*16 + lr)*576 + (ch<<4));
    short8 b0 = XW1p[(kt*4+lg)*128 + colb];
    short8 b1 = XW1p[(kt*4+lg)*128 + colb + 16];
    acc3[0][0] = __builtin_amdgcn_mfma_f32_16x16x32_bf16(b0, a0, acc3[0][0], 0, 0, 0);
    acc3[0][1] = __builtin_amdgcn_mfma_f32_16x16x32_bf16(b1, a0, acc3[0][1], 0, 0, 0);
    acc3[1][0] = __builtin_amdgcn_mfma_f32_16x16x32_bf16(b0, a1, acc3[1][0], 0, 0, 0);
    acc3[1][1] = __builtin_amdgcn_mfma_f32_16x16x32_bf16(b1, a1, acc3[1][1], 0, 0, 0);
  }
  {
    float4 bx0 = *reinterpret_cast<const float4*>(xb1 + c00);
    float4 bx1 = *reinterpret_cast<const float4*>(xb1 + c01);
    float4 xw0 = *reinterpret_cast<const float4*>(xw2 + c00);
    float4 xw1v = *reinterpret_cast<const float4*>(xw2 + c01);
    float ql[2];
    #pragma unroll
    for (int t = 0; t < 2; ++t) {
      ql[t] = 0.f;
      #pragma unroll
      for (int j = 0; j < 2; ++j) {
        const float4 bx = j ? bx1 : bx0;
        const float4 xw = j ? xw1v : xw0;
        ql[t] += fmaxf(acc3[t][j][0] + bx.x, 0.f) * xw.x
               + fmaxf(acc3[t][j][1] + bx.y, 0.f) * xw.y
               + fmaxf(acc3[t][j][2] + bx.z, 0.f) * xw.z
               + fmaxf(acc3[t][j][3] + bx.w, 0.f) * xw.w;
      }
      ql[t] += __shfl_xor(ql[t], 16, 64);
      ql[t] += __shfl_xor(ql[t], 32, 64);
    }
    if (lane < 16) {
      #pragma unroll
      for (int t = 0; t < 2; ++t) ppart[w][rbase + t*16 + lane] = ql[t];
    }
  }
  __syncthreads();  // sync3: qpart ready

  if (SORTED) {
    // qL[row] in eijL, then segment-head threads emit one f32 atomic per run
    if (tid < 64) {
      int wmr = tid >> 5;
      eijL[tid] = xb2[0] + ppart[wmr*4+0][tid] + ppart[wmr*4+1][tid]
                         + ppart[wmr*4+2][tid] + ppart[wmr*4+3][tid];
    }
    __syncthreads();  // sync4: qL ready
    if (tid < 192) {
      int row = tid / 3, c = tid - row*3;
      if (row == 0 || dL[row] != dL[row-1]) {
        int d = dL[row];
        float s = 0.f;
        int r = row;
        while (r < 64 && dL[r] == d) { s += relL[r][c] * eijL[r]; ++r; }
        atomicAdd(dx + d*3 + c, s);
      }
    }
  } else {
    if (tid < 192) {
      int row = tid / 3, c = tid - row*3;
      int wmr = row >> 5;
      float q = xb2[0] + ppart[wmr*4+0][row] + ppart[wmr*4+1][row]
                       + ppart[wmr*4+2][row] + ppart[wmr*4+3][row];
      atomicAdd(dx + dL[row]*3 + c, relL[row][c] * q);
    }
  }
}

// ---- node kernel: h_new = h + MLP([mi,h]); x_new = x + dx ----
template<int MODE>
__global__ __launch_bounds__(256) void node_kernel(
    const float* __restrict__ h, const float* __restrict__ x,
    const float* __restrict__ nb1, const float* __restrict__ nb2,
    const short8* __restrict__ NW1p, const short8* __restrict__ NW2p,
    const unsigned short* __restrict__ miB,
    const unsigned short* __restrict__ hB,
    float* __restrict__ out) {
  __shared__ __align__(16) char c2B[64 * 512];
  __shared__ __align__(16) char y3B[64 * 256];
  const int tid = threadIdx.x;
  const int n0 = blockIdx.x * 64;
  const float* mi = out;

  for (int i = tid; i < 64*32; i += 256) {
    int row = i >> 5, c = i & 31;
    int node = n0 + row;
    U8 u;
    if (node < NNODES) {
      if (c < 16 && MODE >= 1) {
        u.v = *reinterpret_cast<const short8*>(miB + (size_t)node*128 + c*8);
      } else if (c >= 16 && MODE == 2) {
        u.v = *reinterpret_cast<const short8*>(hB + (size_t)node*128 + (c-16)*8);
      } else {
        const float4* p = (c < 16)
          ? reinterpret_cast<const float4*>(mi + (size_t)node*128 + c*8)
          : reinterpret_cast<const float4*>(h + (size_t)node*128 + (c-16)*8);
        float4 a = p[0], b = p[1];
        uint4 uu;
        uu.x = pk2(a.x, a.y); uu.y = pk2(a.z, a.w);
        uu.z = pk2(b.x, b.y); uu.w = pk2(b.z, b.w);
        u.v = *reinterpret_cast<short8*>(&uu);
      }
    } else {
      #pragma unroll
      for (int j = 0; j < 8; ++j) u.u[j] = 0;
    }
    *reinterpret_cast<short8*>(c2B + row*512 + ((c ^ (row&7))<<4)) = u.v;
  }
  __syncthreads();

  const int lane = tid & 63, wave = tid >> 6;
  const int lr = lane & 15, lg = lane >> 4;
  const int rb = wave * 16;
  const int arow = rb + lr;

  f32x4 acc[8];
  #pragma unroll
  for (int nt = 0; nt < 8; ++nt) acc[nt] = (f32x4)0.0f;
  #pragma unroll
  for (int kt = 0; kt < 8; ++kt) {
    int chunk = kt*4 + lg;
    short8 a = *reinterpret_cast<const short8*>(c2B + arow*512 + ((chunk ^ (arow&7))<<4));
    const short8* bp = NW1p + chunk*128 + lr;
    #pragma unroll
    for (int nt = 0; nt < 8; ++nt)
      acc[nt] = __builtin_amdgcn_mfma_f32_16x16x32_bf16(a, bp[nt*16], acc[nt], 0, 0, 0);
  }
  #pragma unroll
  for (int nt = 0; nt < 8; ++nt) {
    int col = nt*16 + lr;
    float bias = nb1[col];
    #pragma unroll
    for (int r = 0; r < 4; ++r) {
      int row = rb + lg*4 + r;
      float v = fmaxf(acc[nt][r] + bias, 0.f);
      *reinterpret_cast<unsigned short*>(y3B + row*256 + (((col>>3) ^ (row&7))<<4) + ((col&7)<<1)) = f2b(v);
    }
  }

  f32x4 acc2[8];
  #pragma unroll
  for (int nt = 0; nt < 8; ++nt) acc2[nt] = (f32x4)0.0f;
  #pragma unroll
  for (int kt = 0; kt < 4; ++kt) {
    int chunk = kt*4 + lg;
    short8 a = *reinterpret_cast<const short8*>(y3B + arow*256 + ((chunk ^ (arow&7))<<4));
    const short8* bp = NW2p + chunk*128 + lr;
    #pragma unroll
    for (int nt = 0; nt < 8; ++nt)
      acc2[nt] = __builtin_amdgcn_mfma_f32_16x16x32_bf16(a, bp[nt*16], acc2[nt], 0, 0, 0);
  }
  __syncthreads();
  #pragma unroll
  for (int nt = 0; nt < 8; ++nt) {
    int col = nt*16 + lr;
    float b2 = nb2[col];
    #pragma unroll
    for (int r = 0; r < 4; ++r) {
      int row = rb + lg*4 + r;
      int node = n0 + row;
      if (node < NNODES) {
        int idx = node*128 + col;
        out[idx] = acc2[nt][r] + b2 + h[idx];
      }
    }
  }

  if (tid < 192) {
    int node = n0 + tid/3;
    if (node < NNODES) {
      int idx = node*3 + (tid%3);
      float* xo = out + NNODES*HID;
      xo[idx] = x[idx] + xo[idx];
    }
  }
}

extern "C" void kernel_launch(void* const* d_in, const int* in_sizes, int n_in,
                              void* d_out, int out_size, void* d_ws, size_t ws_size,
                              hipStream_t stream) {
  const int*   src  = (const int*)  d_in[0];
  const int*   dst  = (const int*)  d_in[1];
  const float* ef   = (const float*)d_in[2];
  const float* h    = (const float*)d_in[3];
  const float* x    = (const float*)d_in[4];
  const float* ew1  = (const float*)d_in[5];
  const float* eb1  = (const float*)d_in[6];
  const float* ew2  = (const float*)d_in[7];
  const float* eb2  = (const float*)d_in[8];
  const float* infw = (const float*)d_in[9];
  const float* infb = (const float*)d_in[10];
  const float* xw1  = (const float*)d_in[11];
  const float* xb1  = (const float*)d_in[12];
  const float* xw2  = (const float*)d_in[13];
  const float* xb2  = (const float*)d_in[14];
  const float* nw1  = (const float*)d_in[15];
  const float* nb1  = (const float*)d_in[16];
  const float* nw2  = (const float*)d_in[17];
  const float* nb2  = (const float*)d_in[18];

  float* out = (float*)d_out;
  float* miF = out;
  float* dxp = out + NNODES*HID;
  unsigned short* wsp = (unsigned short*)d_ws;
  unsigned short* miB = wsp + 118784;
  unsigned short* hBp = miB + (size_t)NNODES*HID;
  int* cntp  = (int*)(wsp + 118784 + 2*(size_t)NNODES*HID);
  int* permp = cntp + 50176;

  const size_t MIN = (size_t)NNODES*HID;
  size_t need1 = (118784u + MIN) * 2u;                               // 13.04 MB
  size_t need2 = (118784u + 2u*MIN) * 2u;                            // 25.84 MB
  size_t need3 = need2 + (50176u + (size_t)NEDGES) * 4u;             // 29.24 MB
  int mode = (ws_size >= need2) ? 2 : (ws_size >= need1 ? 1 : 0);
  int sorted = (mode == 2 && ws_size >= need3) ? 1 : 0;

  if (mode >= 1) {
    hipMemsetAsync(miB, 0, MIN*2, stream);
    hipMemsetAsync(dxp, 0, (size_t)NNODES*3*4, stream);
  } else {
    hipMemsetAsync(d_out, 0, (size_t)out_size * sizeof(float), stream);
  }

  pack_kernel<<<464, 256, 0, stream>>>(ew1, ew2, xw1, nw1, nw2, wsp);
  if (mode == 2) hpack_kernel<<<(NNODES*HID)/(256*8), 256, 0, stream>>>(h, hBp);

  if (sorted) {
    hipMemsetAsync(cntp, 0, 50176*4, stream);
    hist_kernel<<<(NEDGES+255)/256, 256, 0, stream>>>(dst, cntp);
    scan_kernel<<<1, 256, 0, stream>>>(cntp);
    scatter_kernel<<<(NEDGES+255)/256, 256, 0, stream>>>(dst, cntp, permp);
    edge_kernel<2,1><<<NEDGES/64, 512, 0, stream>>>(
        src, dst, ef, h, x, eb1, eb2, infw, infb, xb1, xw2, xb2,
        (const short8*)wsp, (const short8*)(wsp + 36864), (const short8*)(wsp + 53248),
        hBp, permp, miF, miB, dxp);
    node_kernel<2><<<(NNODES + 63)/64, 256, 0, stream>>>(
        h, x, nb1, nb2,
        (const short8*)(wsp + 69632), (const short8*)(wsp + 102400), miB, hBp, out);
  } else if (mode == 2) {
    edge_kernel<2,0><<<NEDGES/64, 512, 0, stream>>>(
        src, dst, ef, h, x, eb1, eb2, infw, infb, xb1, xw2, xb2,
        (const short8*)wsp, (const short8*)(wsp + 36864), (const short8*)(wsp + 53248),
        hBp, permp, miF, miB, dxp);
    node_kernel<2><<<(NNODES + 63)/64, 256, 0, stream>>>(
        h, x, nb1, nb2,
        (const short8*)(wsp + 69632), (const short8*)(wsp + 102400), miB, hBp, out);
  } else if (mode == 1) {
    edge_kernel<1,0><<<NEDGES/64, 512, 0, stream>>>(
        src, dst, ef, h, x, eb1, eb2, infw, infb, xb1, xw2, xb2,
        (const short8*)wsp, (const short8*)(wsp + 36864), (const short8*)(wsp + 53248),
        hBp, permp, miF, miB, dxp);
    node_kernel<1><<<(NNODES + 63)/64, 256, 0, stream>>>(
        h, x, nb1, nb2,
        (const short8*)(wsp + 69632), (const short8*)(wsp + 102400), miB, hBp, out);
  } else {
    edge_kernel<0,0><<<NEDGES/64, 512, 0, stream>>>(
        src, dst, ef, h, x, eb1, eb2, infw, infb, xb1, xw2, xb2,
        (const short8*)wsp, (const short8*)(wsp + 36864), (const short8*)(wsp + 53248),
        hBp, permp, miF, miB, dxp);
    node_kernel<0><<<(NNODES + 63)/64, 256, 0, stream>>>(
        h, x, nb1, nb2,
        (const short8*)(wsp + 69632), (const short8*)(wsp + 102400), miB, hBp, out);
  }
}

// Round 15
// 313.033 us; speedup vs baseline: 3.9190x; 1.5371x over previous
//
#include <hip/hip_runtime.h>

#define HID 128
#define NNODES 50000
#define NEDGES 800000

typedef __attribute__((ext_vector_type(8))) short short8;
typedef __attribute__((ext_vector_type(4))) float f32x4;

union U8 { short8 v; unsigned short u[8]; };

__device__ __forceinline__ unsigned short f2b(float f) {
  unsigned int u = __float_as_uint(f);
  u += 0x7FFFu + ((u >> 16) & 1u);
  return (unsigned short)(u >> 16);
}

// packed RNE f32->bf16x2 — plain C.
// (inline-asm v_cvt_pk_bf16_f32 was proven WRONG on this target in r4 — do not reintroduce)
__device__ __forceinline__ unsigned int pk2(float a, float b) {
  unsigned int ua = __float_as_uint(a);
  ua += 0x7FFFu + ((ua >> 16) & 1u);
  unsigned int ub = __float_as_uint(b);
  ub += 0x7FFFu + ((ub >> 16) & 1u);
  return (ua >> 16) | (ub & 0xFFFF0000u);
}

// cheap round-half-up pack (tie behavior differs from RNE only)
__device__ __forceinline__ unsigned int pk2h(float a, float b) {
  unsigned int ua = __float_as_uint(a) + 0x8000u;
  unsigned int ub = __float_as_uint(b) + 0x8000u;
  return (ua >> 16) | (ub & 0xFFFF0000u);
}

// packed bf16 atomic add (gfx950 ISA; verified r3). Fire-and-forget (no return)
// — pipelines in L2. (Value-RETURNING atomics serialize per address: r13/r14 lesson.)
__device__ __forceinline__ void atomicPkAddBf16(unsigned short* addr, unsigned int packed) {
  asm volatile("global_atomic_pk_add_bf16 %0, %1, off" :: "v"(addr), "v"(packed) : "memory");
}

// stage-zone swizzle (chunks 0..15); same formula on write and read
__device__ __forceinline__ int stage_chunk(int c0, int row) {
  return ((c0 >> 3) ^ (row & 7) ^ (((row >> 2) & 3) << 1)) & 15;
}

// ---- pack weights into bf16 fragment-native layout ----
__global__ __launch_bounds__(256) void pack_kernel(
    const float* __restrict__ ew1, const float* __restrict__ ew2,
    const float* __restrict__ xw1, const float* __restrict__ nw1,
    const float* __restrict__ nw2, unsigned short* __restrict__ ws) {
  int i = blockIdx.x * 256 + threadIdx.x;
  const float* w; int base, ksrc;
  if (i < 36864)       { w = ew1; base = 0;      ksrc = 280; }
  else if (i < 53248)  { w = ew2; base = 36864;  ksrc = 128; }
  else if (i < 69632)  { w = xw1; base = 53248;  ksrc = 128; }
  else if (i < 102400) { w = nw1; base = 69632;  ksrc = 256; }
  else if (i < 118784) { w = nw2; base = 102400; ksrc = 128; }
  else return;
  int li = i - base;
  int j = li & 7, t = li >> 3;
  int col = t & 127, kg = t >> 7;
  int k = kg * 8 + j;
  float v = (k < ksrc) ? w[k * 128 + col] : 0.0f;
  ws[i] = f2b(v);
}

// ---- pre-convert h to bf16 copy hB (hoists per-edge conversion: r6) ----
__global__ __launch_bounds__(256) void hpack_kernel(
    const float* __restrict__ h, unsigned short* __restrict__ hB) {
  int i = blockIdx.x * 256 + threadIdx.x;
  const float4* p = reinterpret_cast<const float4*>(h + (size_t)i * 8);
  float4 a = p[0], b = p[1];
  uint4 u;
  u.x = pk2(a.x, a.y); u.y = pk2(a.z, a.w);
  u.z = pk2(b.x, b.y); u.w = pk2(b.z, b.w);
  *reinterpret_cast<uint4*>(hB + (size_t)i * 8) = u;
}

// ---- edge kernel: 64 edges/block, 8 waves in a 2(M)x4(N) split, swapped MFMA ----
// CHAMPION configuration (r11, 313 µs total). Evidence that this is the floor:
// five schedules (r8-r12: 4/8-wave, N/MxN-split, EPB 64/128, occupancy 44-86%,
// conflicts 14-32M) all converge at 280-305 µs edge; removing 80% of atomic
// traffic via sort+merge (r14) improved edge only 13 µs while sort cost 180 µs.
// Floor = barrier-serialized per-block dependency chain, no pipe saturated.
template<int MODE>
__global__ __launch_bounds__(512, 8) void edge_kernel(
    const int* __restrict__ src, const int* __restrict__ dst,
    const float* __restrict__ ef, const float* __restrict__ h,
    const float* __restrict__ x,
    const float* __restrict__ eb1, const float* __restrict__ eb2,
    const float* __restrict__ infw, const float* __restrict__ infb,
    const float* __restrict__ xb1, const float* __restrict__ xw2,
    const float* __restrict__ xb2,
    const short8* __restrict__ W1p, const short8* __restrict__ W2p,
    const short8* __restrict__ XW1p,
    const unsigned short* __restrict__ hB,
    float* __restrict__ miF, unsigned short* __restrict__ miB,
    float* __restrict__ dx) {
  __shared__ __align__(16) char catB[64 * 576];
  __shared__ int dL[64], sL[64];
  __shared__ float relL[64][3];
  __shared__ float ppart[8][64];   // reused as qpart
  __shared__ float eijL[64];

  const int tid = threadIdx.x;
  const int e0 = blockIdx.x * 64;
  const int lane = tid & 63, w = tid >> 6;       // w in 0..7
  const int wm = w >> 2, wn = w & 3;
  const int lr = lane & 15, lg = lane >> 4;
  const int l7 = lr & 7, l3 = lr & 3;
  const int colb = wn*32 + lr;                   // weight-frag col (j=0); j=1 adds 16
  const int c00 = wn*32 + lg*4, c01 = c00 + 16;  // lane's output cols
  const int rbase = wm*32;                       // wave's first edge row

  // phase 0 (8 threads/edge): meta + edge_feat + gaussians + pad
  {
    int row = tid >> 3, sub = tid & 7;
    int e = e0 + row;
    int s = src[e], d = dst[e];
    if (sub == 0) { sL[row] = s; dL[row] = d; }
    float rx = x[3*d+0] - x[3*s+0];
    float ry = x[3*d+1] - x[3*s+1];
    float rz = x[3*d+2] - x[3*s+2];
    if (sub == 1) { relL[row][0] = rx; relL[row][1] = ry; relL[row][2] = rz; }
    float r = rx*rx + ry*ry + rz*rz;
    const float step = 100.0f / 19.0f;
    const float co = -0.5f / (step * step);
    if (sub < 6) {
      float v4[4];
      if (sub == 0) {
        const float4 efv = reinterpret_cast<const float4*>(ef)[e];
        v4[0]=efv.x; v4[1]=efv.y; v4[2]=efv.z; v4[3]=efv.w;
      } else {
        #pragma unroll
        for (int q = 0; q < 4; ++q) {
          float g = (float)(sub*4 - 4 + q) * step;
          float t = r - g;
          v4[q] = __expf(co * t * t);
        }
      }
      int c = sub*4;
      int chunk = (c>>3) ^ (row&7);
      uint2 pv; pv.x = pk2h(v4[0], v4[1]); pv.y = pk2h(v4[2], v4[3]);
      *reinterpret_cast<uint2*>(catB + row*576 + (chunk<<4) + ((c&7)<<1)) = pv;
    } else if (sub == 6) {
      U8 z;
      #pragma unroll
      for (int j = 0; j < 8; ++j) z.u[j] = 0;
      *reinterpret_cast<short8*>(catB + row*576 + ((32 + (3 ^ (row&3)))<<4)) = z.v;
    }
  }

  // gather h[dst] (chunks 3..18) and h[src] (chunks 19..34)
  #pragma unroll
  for (int it = 0; it < 4; ++it) {
    int i = tid + it*512;
    int row = i >> 5, c = i & 31;
    int node = (c < 16) ? dst[e0+row] : src[e0+row];
    int chunk = 3 + c;
    int sw = (chunk < 32) ? (chunk ^ (row&7)) : (32 + ((chunk&3) ^ (row&3)));
    if (MODE == 2) {
      short8 u = *reinterpret_cast<const short8*>(hB + (size_t)node*128 + (c&15)*8);
      *reinterpret_cast<short8*>(catB + row*576 + (sw<<4)) = u;
    } else {
      const float4* hp = reinterpret_cast<const float4*>(h + (size_t)node*128 + (c&15)*8);
      float4 a = hp[0], b = hp[1];
      uint4 u;
      u.x = pk2(a.x, a.y); u.y = pk2(a.z, a.w);
      u.z = pk2(b.x, b.y); u.w = pk2(b.z, b.w);
      *reinterpret_cast<uint4*>(catB + row*576 + (sw<<4)) = u;
    }
  }

  // prefetch GEMM1 weight fragments for kt=0,1
  short8 p00 = W1p[(0*4+lg)*128 + colb], p01 = W1p[(0*4+lg)*128 + colb + 16];
  short8 p10 = W1p[(1*4+lg)*128 + colb], p11 = W1p[(1*4+lg)*128 + colb + 16];
  __syncthreads();

  // ---- GEMM1: y1 = relu(cat @ W1 + eb1), K=288 ----
  f32x4 acc[2][2];
  #pragma unroll
  for (int t = 0; t < 2; ++t) { acc[t][0] = (f32x4)0.0f; acc[t][1] = (f32x4)0.0f; }
  #pragma unroll
  for (int kt = 0; kt < 9; ++kt) {
    int ch = (kt < 8) ? ((kt*4+lg) ^ l7) : (32 + (lg ^ l3));
    short8 a0 = *reinterpret_cast<const short8*>(catB + (rbase + 0*16 + lr)*576 + (ch<<4));
    short8 a1 = *reinterpret_cast<const short8*>(catB + (rbase + 1*16 + lr)*576 + (ch<<4));
    short8 b0, b1;
    if (kt == 0)      { b0 = p00; b1 = p01; }
    else if (kt == 1) { b0 = p10; b1 = p11; }
    else              { b0 = W1p[(kt*4+lg)*128 + colb]; b1 = W1p[(kt*4+lg)*128 + colb + 16]; }
    acc[0][0] = __builtin_amdgcn_mfma_f32_16x16x32_bf16(b0, a0, acc[0][0], 0, 0, 0);
    acc[0][1] = __builtin_amdgcn_mfma_f32_16x16x32_bf16(b1, a0, acc[0][1], 0, 0, 0);
    acc[1][0] = __builtin_amdgcn_mfma_f32_16x16x32_bf16(b0, a1, acc[1][0], 0, 0, 0);
    acc[1][1] = __builtin_amdgcn_mfma_f32_16x16x32_bf16(b1, a1, acc[1][1], 0, 0, 0);
  }
  __syncthreads();  // all cat reads done before y1 overwrites zone A

  // y1 epilogue
  {
    float4 be0 = *reinterpret_cast<const float4*>(eb1 + c00);
    float4 be1 = *reinterpret_cast<const float4*>(eb1 + c01);
    #pragma unroll
    for (int t = 0; t < 2; ++t) {
      int row = rbase + t*16 + lr;
      char* rowB = catB + row*576;
      #pragma unroll
      for (int j = 0; j < 2; ++j) {
        const float4 be = j ? be1 : be0;
        int c0 = j ? c01 : c00;
        float v0 = fmaxf(acc[t][j][0] + be.x, 0.f);
        float v1 = fmaxf(acc[t][j][1] + be.y, 0.f);
        float v2 = fmaxf(acc[t][j][2] + be.z, 0.f);
        float v3 = fmaxf(acc[t][j][3] + be.w, 0.f);
        uint2 pv; pv.x = pk2h(v0, v1); pv.y = pk2h(v2, v3);
        int chunk = (c0>>3) ^ (row&7);
        *reinterpret_cast<uint2*>(rowB + (chunk<<4) + ((c0&7)<<1)) = pv;
      }
    }
  }
  __syncthreads();  // y1 visible

  // ---- GEMM2: mij = relu(y1 @ W2 + eb2), K=128 ----
  f32x4 acc2[2][2];
  #pragma unroll
  for (int t = 0; t < 2; ++t) { acc2[t][0] = (f32x4)0.0f; acc2[t][1] = (f32x4)0.0f; }
  #pragma unroll
  for (int kt = 0; kt < 4; ++kt) {
    int ch = (kt*4+lg) ^ l7;
    short8 a0 = *reinterpret_cast<const short8*>(catB + (rbase + 0*16 + lr)*576 + (ch<<4));
    short8 a1 = *reinterpret_cast<const short8*>(catB + (rbase + 1*16 + lr)*576 + (ch<<4));
    short8 b0 = W2p[(kt*4+lg)*128 + colb];
    short8 b1 = W2p[(kt*4+lg)*128 + colb + 16];
    acc2[0][0] = __builtin_amdgcn_mfma_f32_16x16x32_bf16(b0, a0, acc2[0][0], 0, 0, 0);
    acc2[0][1] = __builtin_amdgcn_mfma_f32_16x16x32_bf16(b1, a0, acc2[0][1], 0, 0, 0);
    acc2[1][0] = __builtin_amdgcn_mfma_f32_16x16x32_bf16(b0, a1, acc2[1][0], 0, 0, 0);
    acc2[1][1] = __builtin_amdgcn_mfma_f32_16x16x32_bf16(b1, a1, acc2[1][1], 0, 0, 0);
  }
  // epilogue: relu+bias kept in acc2; mij -> chunks 16..31; inf partials
  {
    float4 be0 = *reinterpret_cast<const float4*>(eb2 + c00);
    float4 be1 = *reinterpret_cast<const float4*>(eb2 + c01);
    float4 iw0 = *reinterpret_cast<const float4*>(infw + c00);
    float4 iw1 = *reinterpret_cast<const float4*>(infw + c01);
    float pl[2];
    #pragma unroll
    for (int t = 0; t < 2; ++t) {
      int row = rbase + t*16 + lr;
      char* rowB = catB + row*576;
      pl[t] = 0.f;
      #pragma unroll
      for (int j = 0; j < 2; ++j) {
        const float4 be = j ? be1 : be0;
        const float4 iw = j ? iw1 : iw0;
        int c0 = j ? c01 : c00;
        float v0 = fmaxf(acc2[t][j][0] + be.x, 0.f);
        float v1 = fmaxf(acc2[t][j][1] + be.y, 0.f);
        float v2 = fmaxf(acc2[t][j][2] + be.z, 0.f);
        float v3 = fmaxf(acc2[t][j][3] + be.w, 0.f);
        acc2[t][j][0]=v0; acc2[t][j][1]=v1; acc2[t][j][2]=v2; acc2[t][j][3]=v3;
        pl[t] += v0*iw.x + v1*iw.y + v2*iw.z + v3*iw.w;
        uint2 pv; pv.x = pk2h(v0, v1); pv.y = pk2h(v2, v3);
        int chunk = 16 + ((c0>>3) ^ (row&7));
        *reinterpret_cast<uint2*>(rowB + (chunk<<4) + ((c0&7)<<1)) = pv;
      }
    }
    #pragma unroll
    for (int t = 0; t < 2; ++t) {
      pl[t] += __shfl_xor(pl[t], 16, 64);
      pl[t] += __shfl_xor(pl[t], 32, 64);
    }
    if (lane < 16) {
      #pragma unroll
      for (int t = 0; t < 2; ++t) ppart[w][rbase + t*16 + lane] = pl[t];
    }
  }
  __syncthreads();  // sync1: mij + ppart ready

  if (tid < 64) {
    int wmr = tid >> 5;
    float s2 = infb[0] + ppart[wmr*4+0][tid] + ppart[wmr*4+1][tid]
                       + ppart[wmr*4+2][tid] + ppart[wmr*4+3][tid];
    eijL[tid] = 1.f / (1.f + __expf(-s2));
  }
  __syncthreads();  // sync2: eijL ready

  // ---- stage u = mij*eij into dead y1 zone (chunks 0..15) ----
  if (MODE >= 1) {
    #pragma unroll
    for (int t = 0; t < 2; ++t) {
      int row = rbase + t*16 + lr;
      float e = eijL[row];
      char* rowB = catB + row*576;
      #pragma unroll
      for (int j = 0; j < 2; ++j) {
        int c0 = j ? c01 : c00;
        uint2 pv;
        pv.x = pk2h(acc2[t][j][0]*e, acc2[t][j][1]*e);
        pv.y = pk2h(acc2[t][j][2]*e, acc2[t][j][3]*e);
        *reinterpret_cast<uint2*>(rowB + (stage_chunk(c0, row)<<4) + ((c0&7)<<1)) = pv;
      }
    }
  } else {
    #pragma unroll
    for (int t = 0; t < 2; ++t) {
      int row = rbase + t*16 + lr;
      int d = dL[row];
      float e = eijL[row];
      float* fp = miF + (size_t)d*128;
      #pragma unroll
      for (int j = 0; j < 2; ++j) {
        int c0 = j ? c01 : c00;
        #pragma unroll
        for (int rg = 0; rg < 4; ++rg) atomicAdd(fp + c0 + rg, acc2[t][j][rg]*e);
      }
    }
  }
  __syncthreads();  // sync2b: u staged

  // ---- coalesced scatter FIRST (GEMM3 hides atomic latency) ----
  // per wave instr: 4 dst rows (lg) x 16 consecutive dwords (lr)
  if (MODE >= 1) {
    int col0 = wn*32 + lr*2;
    #pragma unroll
    for (int t2 = 0; t2 < 8; ++t2) {
      int row = rbase + t2*4 + lg;
      int d = dL[row];
      unsigned int val = *reinterpret_cast<const unsigned int*>(
          catB + row*576 + (stage_chunk(col0, row)<<4) + ((col0&7)<<1));
      if (val) atomicPkAddBf16(miB + (size_t)d*128 + col0, val);
    }
  }

  // ---- GEMM3: y2 = relu(mij @ XW1 + xb1); x_scale = y2 . xw2 + xb2 ----
  f32x4 acc3[2][2];
  #pragma unroll
  for (int t = 0; t < 2; ++t) { acc3[t][0] = (f32x4)0.0f; acc3[t][1] = (f32x4)0.0f; }
  #pragma unroll
  for (int kt = 0; kt < 4; ++kt) {
    int ch = 16 + ((kt*4+lg) ^ l7);
    short8 a0 = *reinterpret_cast<const short8*>(catB + (rbase + 0*16 + lr)*576 + (ch<<4));
    short8 a1 = *reinterpret_cast<const short8*>(catB + (rbase + 1*16 + lr)*576 + (ch<<4));
    short8 b0 = XW1p[(kt*4+lg)*128 + colb];
    short8 b1 = XW1p[(kt*4+lg)*128 + colb + 16];
    acc3[0][0] = __builtin_amdgcn_mfma_f32_16x16x32_bf16(b0, a0, acc3[0][0], 0, 0, 0);
    acc3[0][1] = __builtin_amdgcn_mfma_f32_16x16x32_bf16(b1, a0, acc3[0][1], 0, 0, 0);
    acc3[1][0] = __builtin_amdgcn_mfma_f32_16x16x32_bf16(b0, a1, acc3[1][0], 0, 0, 0);
    acc3[1][1] = __builtin_amdgcn_mfma_f32_16x16x32_bf16(b1, a1, acc3[1][1], 0, 0, 0);
  }
  {
    float4 bx0 = *reinterpret_cast<const float4*>(xb1 + c00);
    float4 bx1 = *reinterpret_cast<const float4*>(xb1 + c01);
    float4 xw0 = *reinterpret_cast<const float4*>(xw2 + c00);
    float4 xw1v = *reinterpret_cast<const float4*>(xw2 + c01);
    float ql[2];
    #pragma unroll
    for (int t = 0; t < 2; ++t) {
      ql[t] = 0.f;
      #pragma unroll
      for (int j = 0; j < 2; ++j) {
        const float4 bx = j ? bx1 : bx0;
        const float4 xw = j ? xw1v : xw0;
        ql[t] += fmaxf(acc3[t][j][0] + bx.x, 0.f) * xw.x
               + fmaxf(acc3[t][j][1] + bx.y, 0.f) * xw.y
               + fmaxf(acc3[t][j][2] + bx.z, 0.f) * xw.z
               + fmaxf(acc3[t][j][3] + bx.w, 0.f) * xw.w;
      }
      ql[t] += __shfl_xor(ql[t], 16, 64);
      ql[t] += __shfl_xor(ql[t], 32, 64);
    }
    if (lane < 16) {
      #pragma unroll
      for (int t = 0; t < 2; ++t) ppart[w][rbase + t*16 + lane] = ql[t];
    }
  }
  __syncthreads();  // sync3: qpart ready

  if (tid < 192) {
    int row = tid / 3, c = tid - row*3;
    int wmr = row >> 5;
    float q = xb2[0] + ppart[wmr*4+0][row] + ppart[wmr*4+1][row]
                     + ppart[wmr*4+2][row] + ppart[wmr*4+3][row];
    atomicAdd(dx + dL[row]*3 + c, relL[row][c] * q);
  }
}

// ---- node kernel: h_new = h + MLP([mi,h]); x_new = x + dx ----
template<int MODE>
__global__ __launch_bounds__(256) void node_kernel(
    const float* __restrict__ h, const float* __restrict__ x,
    const float* __restrict__ nb1, const float* __restrict__ nb2,
    const short8* __restrict__ NW1p, const short8* __restrict__ NW2p,
    const unsigned short* __restrict__ miB,
    const unsigned short* __restrict__ hB,
    float* __restrict__ out) {
  __shared__ __align__(16) char c2B[64 * 512];
  __shared__ __align__(16) char y3B[64 * 256];
  const int tid = threadIdx.x;
  const int n0 = blockIdx.x * 64;
  const float* mi = out;

  for (int i = tid; i < 64*32; i += 256) {
    int row = i >> 5, c = i & 31;
    int node = n0 + row;
    U8 u;
    if (node < NNODES) {
      if (c < 16 && MODE >= 1) {
        u.v = *reinterpret_cast<const short8*>(miB + (size_t)node*128 + c*8);
      } else if (c >= 16 && MODE == 2) {
        u.v = *reinterpret_cast<const short8*>(hB + (size_t)node*128 + (c-16)*8);
      } else {
        const float4* p = (c < 16)
          ? reinterpret_cast<const float4*>(mi + (size_t)node*128 + c*8)
          : reinterpret_cast<const float4*>(h + (size_t)node*128 + (c-16)*8);
        float4 a = p[0], b = p[1];
        uint4 uu;
        uu.x = pk2(a.x, a.y); uu.y = pk2(a.z, a.w);
        uu.z = pk2(b.x, b.y); uu.w = pk2(b.z, b.w);
        u.v = *reinterpret_cast<short8*>(&uu);
      }
    } else {
      #pragma unroll
      for (int j = 0; j < 8; ++j) u.u[j] = 0;
    }
    *reinterpret_cast<short8*>(c2B + row*512 + ((c ^ (row&7))<<4)) = u.v;
  }
  __syncthreads();

  const int lane = tid & 63, wave = tid >> 6;
  const int lr = lane & 15, lg = lane >> 4;
  const int rb = wave * 16;
  const int arow = rb + lr;

  f32x4 acc[8];
  #pragma unroll
  for (int nt = 0; nt < 8; ++nt) acc[nt] = (f32x4)0.0f;
  #pragma unroll
  for (int kt = 0; kt < 8; ++kt) {
    int chunk = kt*4 + lg;
    short8 a = *reinterpret_cast<const short8*>(c2B + arow*512 + ((chunk ^ (arow&7))<<4));
    const short8* bp = NW1p + chunk*128 + lr;
    #pragma unroll
    for (int nt = 0; nt < 8; ++nt)
      acc[nt] = __builtin_amdgcn_mfma_f32_16x16x32_bf16(a, bp[nt*16], acc[nt], 0, 0, 0);
  }
  #pragma unroll
  for (int nt = 0; nt < 8; ++nt) {
    int col = nt*16 + lr;
    float bias = nb1[col];
    #pragma unroll
    for (int r = 0; r < 4; ++r) {
      int row = rb + lg*4 + r;
      float v = fmaxf(acc[nt][r] + bias, 0.f);
      *reinterpret_cast<unsigned short*>(y3B + row*256 + (((col>>3) ^ (row&7))<<4) + ((col&7)<<1)) = f2b(v);
    }
  }

  f32x4 acc2[8];
  #pragma unroll
  for (int nt = 0; nt < 8; ++nt) acc2[nt] = (f32x4)0.0f;
  #pragma unroll
  for (int kt = 0; kt < 4; ++kt) {
    int chunk = kt*4 + lg;
    short8 a = *reinterpret_cast<const short8*>(y3B + arow*256 + ((chunk ^ (arow&7))<<4));
    const short8* bp = NW2p + chunk*128 + lr;
    #pragma unroll
    for (int nt = 0; nt < 8; ++nt)
      acc2[nt] = __builtin_amdgcn_mfma_f32_16x16x32_bf16(a, bp[nt*16], acc2[nt], 0, 0, 0);
  }
  __syncthreads();
  #pragma unroll
  for (int nt = 0; nt < 8; ++nt) {
    int col = nt*16 + lr;
    float b2 = nb2[col];
    #pragma unroll
    for (int r = 0; r < 4; ++r) {
      int row = rb + lg*4 + r;
      int node = n0 + row;
      if (node < NNODES) {
        int idx = node*128 + col;
        out[idx] = acc2[nt][r] + b2 + h[idx];
      }
    }
  }

  if (tid < 192) {
    int node = n0 + tid/3;
    if (node < NNODES) {
      int idx = node*3 + (tid%3);
      float* xo = out + NNODES*HID;
      xo[idx] = x[idx] + xo[idx];
    }
  }
}

extern "C" void kernel_launch(void* const* d_in, const int* in_sizes, int n_in,
                              void* d_out, int out_size, void* d_ws, size_t ws_size,
                              hipStream_t stream) {
  const int*   src  = (const int*)  d_in[0];
  const int*   dst  = (const int*)  d_in[1];
  const float* ef   = (const float*)d_in[2];
  const float* h    = (const float*)d_in[3];
  const float* x    = (const float*)d_in[4];
  const float* ew1  = (const float*)d_in[5];
  const float* eb1  = (const float*)d_in[6];
  const float* ew2  = (const float*)d_in[7];
  const float* eb2  = (const float*)d_in[8];
  const float* infw = (const float*)d_in[9];
  const float* infb = (const float*)d_in[10];
  const float* xw1  = (const float*)d_in[11];
  const float* xb1  = (const float*)d_in[12];
  const float* xw2  = (const float*)d_in[13];
  const float* xb2  = (const float*)d_in[14];
  const float* nw1  = (const float*)d_in[15];
  const float* nb1  = (const float*)d_in[16];
  const float* nw2  = (const float*)d_in[17];
  const float* nb2  = (const float*)d_in[18];

  float* out = (float*)d_out;
  float* miF = out;
  float* dxp = out + NNODES*HID;
  unsigned short* wsp = (unsigned short*)d_ws;
  unsigned short* miB = wsp + 118784;
  unsigned short* hBp = miB + (size_t)NNODES*HID;

  const size_t MIN = (size_t)NNODES*HID;
  size_t need1 = (118784u + MIN) * 2u;
  size_t need2 = (118784u + 2u*MIN) * 2u;
  int mode = (ws_size >= need2) ? 2 : (ws_size >= need1 ? 1 : 0);

  if (mode >= 1) {
    hipMemsetAsync(miB, 0, MIN*2, stream);
    hipMemsetAsync(dxp, 0, (size_t)NNODES*3*4, stream);
  } else {
    hipMemsetAsync(d_out, 0, (size_t)out_size * sizeof(float), stream);
  }

  pack_kernel<<<464, 256, 0, stream>>>(ew1, ew2, xw1, nw1, nw2, wsp);
  if (mode == 2) hpack_kernel<<<(NNODES*HID)/(256*8), 256, 0, stream>>>(h, hBp);

  if (mode == 2) {
    edge_kernel<2><<<NEDGES/64, 512, 0, stream>>>(
        src, dst, ef, h, x, eb1, eb2, infw, infb, xb1, xw2, xb2,
        (const short8*)wsp, (const short8*)(wsp + 36864), (const short8*)(wsp + 53248),
        hBp, miF, miB, dxp);
    node_kernel<2><<<(NNODES + 63)/64, 256, 0, stream>>>(
        h, x, nb1, nb2,
        (const short8*)(wsp + 69632), (const short8*)(wsp + 102400), miB, hBp, out);
  } else if (mode == 1) {
    edge_kernel<1><<<NEDGES/64, 512, 0, stream>>>(
        src, dst, ef, h, x, eb1, eb2, infw, infb, xb1, xw2, xb2,
        (const short8*)wsp, (const short8*)(wsp + 36864), (const short8*)(wsp + 53248),
        hBp, miF, miB, dxp);
    node_kernel<1><<<(NNODES + 63)/64, 256, 0, stream>>>(
        h, x, nb1, nb2,
        (const short8*)(wsp + 69632), (const short8*)(wsp + 102400), miB, hBp, out);
  } else {
    edge_kernel<0><<<NEDGES/64, 512, 0, stream>>>(
        src, dst, ef, h, x, eb1, eb2, infw, infb, xb1, xw2, xb2,
        (const short8*)wsp, (const short8*)(wsp + 36864), (const short8*)(wsp + 53248),
        hBp, miF, miB, dxp);
    node_kernel<0><<<(NNODES + 63)/64, 256, 0, stream>>>(
        h, x, nb1, nb2,
        (const short8*)(wsp + 69632), (const short8*)(wsp + 102400), miB, hBp, out);
  }
}